// Round 1
// baseline (28.448 us; speedup 1.0000x reference)
//
#include <hip/hip_runtime.h>

// FieldSampler: out[b,n,:] = lerp(field[b,il,:], field[b,ir,:], w)
// where il = searchsorted(grid[b,:], clamp(pos), side="right") - 1, clamped to [0, G-2].
//
// One 64-lane wave per sample (b,n); each lane processes one float4 of D=256.
// Binary search is wave-uniform (all lanes same address -> broadcast loads).

__global__ __launch_bounds__(256) void FieldSampler_kernel(
    const float* __restrict__ field,   // [B, G, D]
    const float* __restrict__ grid,    // [B, G]
    const float* __restrict__ pos,     // [B, N]
    float* __restrict__ out,           // [B, N, D]
    int B, int G, int N, int D)
{
    const int wave = threadIdx.x >> 6;           // 0..3
    const int lane = threadIdx.x & 63;           // 0..63
    const int s = blockIdx.x * 4 + wave;         // sample index in [0, B*N)
    if (s >= B * N) return;
    const int b = s / N;
    const int n = s - b * N;

    const float* __restrict__ g = grid + (size_t)b * G;
    const float p  = pos[(size_t)b * N + n];
    const float g0 = g[0];
    const float gL = g[G - 1];
    const float pc = fminf(fmaxf(p, g0), gL);

    // searchsorted(side="right"): first index where g[idx] > pc
    int lo = 0, hi = G;
    #pragma unroll 1
    while (lo < hi) {
        const int mid = (lo + hi) >> 1;
        if (g[mid] <= pc) lo = mid + 1; else hi = mid;
    }
    int il = lo - 1;
    il = il < 0 ? 0 : (il > G - 2 ? G - 2 : il);
    const int ir = il + 1;

    const float gl = g[il];
    const float gr = g[ir];
    const float denom = fmaxf(gr - gl, 1e-8f);
    const float wr = (pc - gl) / denom;
    const float wl = 1.0f - wr;

    const float4* __restrict__ fl =
        (const float4*)(field + ((size_t)b * G + il) * D);
    const float4* __restrict__ fr =
        (const float4*)(field + ((size_t)b * G + ir) * D);
    float4* __restrict__ o = (float4*)(out + ((size_t)b * N + n) * D);

    // D = 256 floats = 64 float4 -> one per lane
    const float4 a = fl[lane];
    const float4 c = fr[lane];
    float4 r;
    r.x = wl * a.x + wr * c.x;
    r.y = wl * a.y + wr * c.y;
    r.z = wl * a.z + wr * c.z;
    r.w = wl * a.w + wr * c.w;
    o[lane] = r;
}

extern "C" void kernel_launch(void* const* d_in, const int* in_sizes, int n_in,
                              void* d_out, int out_size, void* d_ws, size_t ws_size,
                              hipStream_t stream) {
    const float* field = (const float*)d_in[0];   // [B, G, D]
    const float* grid  = (const float*)d_in[1];   // [B, G, 1]
    const float* pos   = (const float*)d_in[2];   // [B, N, 1]
    float* out = (float*)d_out;                   // [B, N, D]

    const int B = 8;
    const int D = in_sizes[0] / in_sizes[1];      // 256
    const int G = in_sizes[1] / B;                // 4096
    const int N = in_sizes[2] / B;                // 4096

    const int samples = B * N;                    // 32768
    const int blocks = (samples + 3) / 4;         // 4 waves (samples) per block

    FieldSampler_kernel<<<blocks, 256, 0, stream>>>(field, grid, pos, out, B, G, N, D);
}

// Round 3
// 19.158 us; speedup vs baseline: 1.4849x; 1.4849x over previous
//
#include <hip/hip_runtime.h>

// FieldSampler: out[b,n,:] = lerp(field[b,il,:], field[b,ir,:], w)
// il = searchsorted(grid[b,:], clamp(pos), "right") - 1, clamped to [0, G-2].
//
// One 64-lane wave per sample; each lane handles one float4 of D=256.
// XCD-aware swizzle: blocks are dispatched round-robin across 8 XCDs, so
// batch index = blockIdx.x & 7 pins each batch's 4 MB field slab into ONE
// XCD's 4 MiB L2. Non-temporal out stores keep the slab resident.

typedef float f32x4 __attribute__((ext_vector_type(4)));

__global__ __launch_bounds__(256) void FieldSampler_kernel(
    const float* __restrict__ field,   // [B, G, D]
    const float* __restrict__ grid,    // [B, G]
    const float* __restrict__ pos,     // [B, N]
    float* __restrict__ out,           // [B, N, D]
    int B, int G, int N, int D)
{
    const int wave = threadIdx.x >> 6;           // 0..3
    const int lane = threadIdx.x & 63;           // 0..63

    // XCD swizzle: consecutive blocks go to consecutive XCDs (round-robin),
    // so use low 3 bits as the batch index -> batch b lives on XCD b.
    const int b = blockIdx.x & 7;                // batch == XCD
    const int n = ((blockIdx.x >> 3) << 2) + wave;
    if (b >= B || n >= N) return;

    const float* __restrict__ g = grid + (size_t)b * G;
    const float p  = pos[(size_t)b * N + n];
    const float g0 = g[0];
    const float gL = g[G - 1];
    const float pc = fminf(fmaxf(p, g0), gL);

    // searchsorted(side="right"): first index where g[idx] > pc
    int lo = 0, hi = G;
    #pragma unroll 1
    while (lo < hi) {
        const int mid = (lo + hi) >> 1;
        if (g[mid] <= pc) lo = mid + 1; else hi = mid;
    }
    int il = lo - 1;
    il = il < 0 ? 0 : (il > G - 2 ? G - 2 : il);
    const int ir = il + 1;

    const float gl = g[il];
    const float gr = g[ir];
    const float denom = fmaxf(gr - gl, 1e-8f);
    const float wr = (pc - gl) / denom;
    const float wl = 1.0f - wr;

    const f32x4* __restrict__ fl =
        (const f32x4*)(field + ((size_t)b * G + il) * D);
    const f32x4* __restrict__ fr =
        (const f32x4*)(field + ((size_t)b * G + ir) * D);
    f32x4* __restrict__ o = (f32x4*)(out + ((size_t)b * N + n) * D);

    const f32x4 a = fl[lane];
    const f32x4 c = fr[lane];
    f32x4 r = wl * a + wr * c;
    __builtin_nontemporal_store(r, &o[lane]);
}

extern "C" void kernel_launch(void* const* d_in, const int* in_sizes, int n_in,
                              void* d_out, int out_size, void* d_ws, size_t ws_size,
                              hipStream_t stream) {
    const float* field = (const float*)d_in[0];   // [B, G, D]
    const float* grid  = (const float*)d_in[1];   // [B, G, 1]
    const float* pos   = (const float*)d_in[2];   // [B, N, 1]
    float* out = (float*)d_out;                   // [B, N, D]

    const int B = 8;
    const int D = in_sizes[0] / in_sizes[1];      // 256
    const int G = in_sizes[1] / B;                // 4096
    const int N = in_sizes[2] / B;                // 4096

    // B*N samples, 4 samples (waves) per block. B==8 makes the &7 swizzle
    // exactly cover batches; N%4==0 makes it exact.
    const int blocks = (B * N) / 4;               // 8192

    FieldSampler_kernel<<<blocks, 256, 0, stream>>>(field, grid, pos, out, B, G, N, D);
}

// Round 4
// 13.048 us; speedup vs baseline: 2.1803x; 1.4683x over previous
//
#include <hip/hip_runtime.h>

// FieldSampler: out[b,n,:] = lerp(field[b,il,:], field[b,ir,:], w)
// il = searchsorted(grid[b,:], clamp(pos), "right") - 1, clamped to [0, G-2].
//
// Fast path (G == 4096 = 64*64):
//   - one 64-lane wave processes SPW=4 samples of one batch
//   - 64-ary 2-round lane-parallel search:
//       round 1: gv1 = g[lane*64] (loaded once/wave), ballot(gv1<=pc) -> bucket
//       round 2: gv2 = g[base2+lane] (256B coalesced), ballot -> exact index
//     count(g<=pc) == searchsorted_right, computed hierarchically (exact,
//     duplicate-safe: all idx<base2 are <=pc, all idx>=base2+64 are >pc).
//   - ballot/popc are wave-uniform -> search index lives in SGPRs
//   - XCD swizzle: batch = blockIdx.x & 7 pins each 4MB field slab in one L2
//   - non-temporal out stores (written once, never re-read)

typedef float f32x4 __attribute__((ext_vector_type(4)));

constexpr int SPW = 4;  // samples per wave

__global__ __launch_bounds__(256) void FieldSampler_fast(
    const float* __restrict__ field,   // [B, G, D]
    const float* __restrict__ grid,    // [B, G]
    const float* __restrict__ pos,     // [B, N]
    float* __restrict__ out,           // [B, N, D]
    int G, int N, int D)
{
    const int wave = threadIdx.x >> 6;
    const int lane = threadIdx.x & 63;

    const int b  = blockIdx.x & 7;                              // batch == XCD
    const int n0 = (((blockIdx.x >> 3) << 2) + wave) * SPW;

    const float* __restrict__ g = grid + (size_t)b * G;

    // round-1 probe values, loaded ONCE per wave (L1-resident grid)
    const float gv1 = g[lane << 6];          // g[lane*64]
    const float g0  = g[0];
    const float gL  = g[G - 1];

    // 4 sample positions: one wave-uniform 16B load
    const f32x4 p4 = *(const f32x4*)(pos + (size_t)b * N + n0);

    float pc[SPW];
    int   base2[SPW];
    #pragma unroll
    for (int k = 0; k < SPW; ++k) {
        pc[k] = fminf(fmaxf(p4[k], g0), gL);
        unsigned long long m1 = __ballot(gv1 <= pc[k]);
        int cnt1 = __popcll(m1);             // >= 1 (g[0] <= pc)
        base2[k] = (cnt1 - 1) << 6;
    }

    // round-2 probes: SPW independent coalesced 256B loads
    float gv2[SPW];
    #pragma unroll
    for (int k = 0; k < SPW; ++k) gv2[k] = g[base2[k] + lane];

    int   il[SPW];
    float wl[SPW], wr[SPW];
    #pragma unroll
    for (int k = 0; k < SPW; ++k) {
        unsigned long long m2 = __ballot(gv2[k] <= pc[k]);
        int cnt2 = __popcll(m2);             // >= 1
        int idx = base2[k] + cnt2 - 1;       // searchsorted_right - 1
        idx = idx > G - 2 ? G - 2 : idx;
        il[k] = idx;
        // scalar (wave-uniform) loads, off the gather critical path
        const float gl = g[idx];
        const float gr = g[idx + 1];
        const float w  = (pc[k] - gl) / fmaxf(gr - gl, 1e-8f);
        wr[k] = w;
        wl[k] = 1.0f - w;
    }

    // gather + lerp + stream-store, 4 samples (4KB contiguous out per wave)
    const size_t fbase = (size_t)b * G * D + ((size_t)lane << 2);
    float* obase = out + ((size_t)b * N + n0) * D + ((size_t)lane << 2);
    #pragma unroll
    for (int k = 0; k < SPW; ++k) {
        const f32x4 a = *(const f32x4*)(field + fbase + (size_t)il[k] * D);
        const f32x4 c = *(const f32x4*)(field + fbase + (size_t)(il[k] + 1) * D);
        f32x4 r = wl[k] * a + wr[k] * c;
        __builtin_nontemporal_store(r, (f32x4*)(obase + (size_t)k * D));
    }
}

// Generic fallback (any G): per-wave binary search, one sample per wave.
__global__ __launch_bounds__(256) void FieldSampler_generic(
    const float* __restrict__ field,
    const float* __restrict__ grid,
    const float* __restrict__ pos,
    float* __restrict__ out,
    int B, int G, int N, int D)
{
    const int wave = threadIdx.x >> 6;
    const int lane = threadIdx.x & 63;
    const int s = blockIdx.x * 4 + wave;
    if (s >= B * N) return;
    const int b = s / N;
    const int n = s - b * N;

    const float* __restrict__ g = grid + (size_t)b * G;
    const float p  = pos[(size_t)b * N + n];
    const float pc = fminf(fmaxf(p, g[0]), g[G - 1]);

    int lo = 0, hi = G;
    #pragma unroll 1
    while (lo < hi) {
        const int mid = (lo + hi) >> 1;
        if (g[mid] <= pc) lo = mid + 1; else hi = mid;
    }
    int il = lo - 1;
    il = il < 0 ? 0 : (il > G - 2 ? G - 2 : il);

    const float gl = g[il];
    const float gr = g[il + 1];
    const float w  = (pc - gl) / fmaxf(gr - gl, 1e-8f);

    const f32x4 a = *(const f32x4*)(field + ((size_t)b * G + il) * D + (lane << 2));
    const f32x4 c = *(const f32x4*)(field + ((size_t)b * G + il + 1) * D + (lane << 2));
    f32x4 r = (1.0f - w) * a + w * c;
    __builtin_nontemporal_store(r, (f32x4*)(out + ((size_t)b * N + n) * D + (lane << 2)));
}

extern "C" void kernel_launch(void* const* d_in, const int* in_sizes, int n_in,
                              void* d_out, int out_size, void* d_ws, size_t ws_size,
                              hipStream_t stream) {
    const float* field = (const float*)d_in[0];   // [B, G, D]
    const float* grid  = (const float*)d_in[1];   // [B, G, 1]
    const float* pos   = (const float*)d_in[2];   // [B, N, 1]
    float* out = (float*)d_out;                   // [B, N, D]

    const int B = 8;
    const int D = in_sizes[0] / in_sizes[1];      // 256
    const int G = in_sizes[1] / B;                // 4096
    const int N = in_sizes[2] / B;                // 4096

    if (B == 8 && G == 4096 && D == 256 && (N % (4 * SPW)) == 0) {
        // 4 waves/block * SPW samples = 16 samples/block
        const int blocks = (B * N) / (4 * SPW);   // 2048
        FieldSampler_fast<<<blocks, 256, 0, stream>>>(field, grid, pos, out, G, N, D);
    } else {
        const int blocks = (B * N + 3) / 4;
        FieldSampler_generic<<<blocks, 256, 0, stream>>>(field, grid, pos, out, B, G, N, D);
    }
}